// Round 21
// baseline (913.968 us; speedup 1.0000x reference)
//
#include <hip/hip_runtime.h>
#include <hip/hip_bf16.h>
#include <math.h>

typedef __attribute__((ext_vector_type(8))) _Float16 half8;
typedef __attribute__((ext_vector_type(4))) _Float16 half4;
typedef __attribute__((ext_vector_type(4))) float f32x4;
typedef __attribute__((ext_vector_type(4))) unsigned int u32x4;

#define FDIM 128
#define EPSBN 1e-5f
#define HSCALE_INV 0.015625f   // h presented to MFMA as h/64
#define WSCALE 64.0f           // node-weight rows pre-scaled (exact pow2)
#define LOG2E 1.4426950408889634f
#define LN2   0.6931471805599453f

// ======== weight prep: node W in register-fragment layout, x64 x log2e ========
__global__ void prep_wn2(const float* __restrict__ Wf, const float* __restrict__ Ws,
                         _Float16* __restrict__ Wn2) {
    int idx = blockIdx.x * 256 + threadIdx.x;
    const int total = 6 * 65536;
    if (idx >= total) return;
    int j = idx & 7;
    int l15 = (idx >> 3) & 15;
    int lhi = (idx >> 7) & 3;
    int cb = (idx >> 9) & 31;
    int c4 = (idx >> 14) & 3;
    int i = idx >> 16;
    int col512 = cb * 16 + l15;
    int which = col512 >> 8;
    int colc = col512 & 255;
    int p = (colc >> 4) & 1;
    int f = ((colc >> 5) << 4) | (colc & 15);
    int k = c4 * 32 + lhi * 8 + j;
    int row = which * 128 + k;
    size_t o = ((size_t)i * 297 + row) * 128 + f;
    Wn2[idx] = (_Float16)((p ? Ws[o] : Wf[o]) * (WSCALE * LOG2E));
}

// ======== weight prep: ea part, register-fragment layout, x log2e ========
__global__ void prep_wb2(const float* __restrict__ Wf, const float* __restrict__ Ws,
                         _Float16* __restrict__ Wb2) {
    int idx = blockIdx.x * 256 + threadIdx.x;
    const int total = 6 * 16384;
    if (idx >= total) return;
    int j = idx & 7;
    int l15 = (idx >> 3) & 15;
    int lhi = (idx >> 7) & 3;
    int cb = (idx >> 9) & 15;
    int c2 = (idx >> 13) & 1;
    int i = idx >> 14;
    int k = c2 * 32 + lhi * 8 + j;
    int colc = cb * 16 + l15;
    int p = (colc >> 4) & 1;
    int f = ((colc >> 5) << 4) | (colc & 15);
    float v = 0.0f;
    if (k < 41) {
        size_t o = ((size_t)i * 297 + 256 + k) * 128 + f;
        v = (p ? Ws[o] : Wf[o]) * LOG2E;
    }
    Wb2[idx] = (_Float16)v;
}

// ======== weight prep: embed W fragments We[c4][cb(8)][lhi][l15][j], K pad 128 ==
__global__ void prep_we(const float* __restrict__ embW, _Float16* __restrict__ We) {
    int idx = blockIdx.x * 256 + threadIdx.x;
    if (idx >= 16384) return;
    int j = idx & 7;
    int l15 = (idx >> 3) & 15;
    int lhi = (idx >> 7) & 3;
    int cb = (idx >> 9) & 7;
    int c4 = (idx >> 12) & 3;
    int k = c4 * 32 + lhi * 8 + j;
    int f = cb * 16 + l15;
    We[idx] = (_Float16)((k < 98) ? embW[k * 128 + f] : 0.0f);
}

// ======== head weight transpose ========
__global__ void prep_ht(const float* __restrict__ pW, const float* __restrict__ f1W,
                        const float* __restrict__ f2W, const float* __restrict__ d1W,
                        const float* __restrict__ d2W, float* __restrict__ HT) {
    int idx = blockIdx.x * 256 + threadIdx.x;
    if (idx < 32768) {
        int o = idx >> 8, k = idx & 255;
        HT[o * 256 + k] = pW[k * 128 + o];
    } else if (idx < 65536) {
        int r = idx - 32768; int o = r >> 7, k = r & 127;
        HT[32768 + o * 128 + k] = f1W[k * 256 + o];
    } else if (idx < 98304) {
        int r = idx - 65536; int o = r >> 8, k = r & 255;
        HT[65536 + o * 256 + k] = f2W[k * 128 + o];
    } else if (idx < 131072) {
        int r = idx - 98304; int o = r >> 7, k = r & 127;
        HT[98304 + o * 128 + k] = d1W[k * 256 + o];
    } else if (idx < 229376) {
        int r = idx - 131072; int o = r >> 8, k = r & 255;
        HT[131072 + o * 256 + k] = d2W[k * 384 + o];
    }
}

// ======== BN affine composition: xo = agg*A + h*B + C ; A absorbs ln2 ========
__global__ void prep_bn(const float* __restrict__ bing, const float* __restrict__ binb,
                        const float* __restrict__ binm, const float* __restrict__ binv,
                        const float* __restrict__ bog, const float* __restrict__ bob,
                        const float* __restrict__ bom, const float* __restrict__ bov,
                        float* __restrict__ ABC) {
    int idx = blockIdx.x * 128 + threadIdx.x;
    if (idx >= 6 * 128) return;
    int f = idx & 127;
    int i = idx >> 7;
    int o = i * 128 + f;
    float gin_ = bing[o] / sqrtf(binv[o] + EPSBN);
    float gout_ = bog[o] / sqrtf(bov[o] + EPSBN);
    ABC[i * 384 + f] = gin_ * gout_ * LN2;
    ABC[i * 384 + 128 + f] = gout_ + ((i > 0) ? 1.0f : 0.0f);
    ABC[i * 384 + 256 + f] = (binb[o] - binm[o] * gin_ - bom[o]) * gout_ + bob[o];
}

// ======== sorting ========
__global__ void hist_k(const int* __restrict__ dstI, int* __restrict__ cnt, int E) {
    int e = blockIdx.x * 256 + threadIdx.x;
    if (e < E) atomicAdd(&cnt[dstI[e]], 1);
}

__global__ void scan_k(const int* __restrict__ cnt, int* __restrict__ cursor, int N) {
    __shared__ int part[256];
    int t = threadIdx.x;
    int chunk = (N + 255) / 256;
    int lo = t * chunk, hi = lo + chunk; if (hi > N) hi = N;
    int s = 0;
    for (int i = lo; i < hi; ++i) s += cnt[i];
    part[t] = s;
    __syncthreads();
    for (int d = 1; d < 256; d <<= 1) {
        int v = (t >= d) ? part[t - d] : 0;
        __syncthreads();
        part[t] += v;
        __syncthreads();
    }
    int run = (t > 0) ? part[t - 1] : 0;
    for (int i = lo; i < hi; ++i) { cursor[i] = run; run += cnt[i]; }
}

__global__ void scatter_k(const int* __restrict__ srcI, const int* __restrict__ dstI,
                          int* __restrict__ cursor, unsigned* __restrict__ sdS,
                          int* __restrict__ invE, int E) {
    int e = blockIdx.x * 256 + threadIdx.x;
    if (e >= E) return;
    int d = dstI[e];
    int pos = atomicAdd(&cursor[d], 1);
    sdS[pos] = (unsigned)srcI[e] | ((unsigned)d << 16);
    invE[e] = pos;
}

__global__ void permute_ea2(const float* __restrict__ ea, const int* __restrict__ invE,
                            _Float16* __restrict__ eaH, int E) {
    int e = blockIdx.x * 4 + (threadIdx.x >> 6);
    int c = threadIdx.x & 63;
    if (e >= E) return;
    float v = (c < 41) ? ea[(size_t)e * 41 + c] : 0.0f;
    int pos = invE[e];
    eaH[(size_t)pos * 64 + c] = (_Float16)v;
}

// ======== embed via MFMA ========
__global__ __launch_bounds__(256, 4)
void embed_mm(const float* __restrict__ x, const _Float16* __restrict__ We,
              const float* __restrict__ b, float* __restrict__ h, int N) {
    __shared__ __align__(16) _Float16 xt[32 * 128];
    const int tid = threadIdx.x;
    const int nb = blockIdx.x * 32;

    {
        int e = tid >> 3, t = tid & 7;
        int node = nb + e; if (node >= N) node = N - 1;
        const float* row = x + (size_t)node * 98;
        __align__(16) _Float16 tmp[16];
        #pragma unroll
        for (int u = 0; u < 16; ++u) {
            int c = t * 16 + u;
            tmp[u] = (c < 98) ? (_Float16)row[c] : (_Float16)0.f;
        }
        int swz = (e & 7) << 4;
        *(u32x4*)((char*)xt + e * 256 + (((2 * t) * 16) ^ swz)) = *(u32x4*)tmp;
        *(u32x4*)((char*)xt + e * 256 + (((2 * t + 1) * 16) ^ swz)) = *(u32x4*)(tmp + 8);
    }
    __syncthreads();

    const int wid = tid >> 6;
    const int lane = tid & 63;
    const int l15 = lane & 15;
    const int lhi = lane >> 4;
    const int swzA = (l15 & 7) << 4;

    f32x4 acc[2][2];
    #pragma unroll
    for (int m = 0; m < 2; ++m)
        #pragma unroll
        for (int n = 0; n < 2; ++n) acc[m][n] = (f32x4){0.f, 0.f, 0.f, 0.f};

    #pragma unroll
    for (int c4 = 0; c4 < 4; ++c4) {
        half8 a[2];
        #pragma unroll
        for (int m = 0; m < 2; ++m) {
            int r = m * 16 + l15;
            a[m] = *(const half8*)((const char*)xt + r * 256 + ((c4 * 64 + lhi * 16) ^ swzA));
        }
        #pragma unroll
        for (int n = 0; n < 2; ++n) {
            int cb = wid * 2 + n;
            const half8 bf = *(const half8*)(We + ((((size_t)c4 * 8 + cb) * 4 + lhi) * 16 + l15) * 8);
            #pragma unroll
            for (int m = 0; m < 2; ++m)
                acc[m][n] = __builtin_amdgcn_mfma_f32_16x16x32_f16(a[m], bf, acc[m][n], 0, 0, 0);
        }
    }

    #pragma unroll
    for (int m = 0; m < 2; ++m) {
        #pragma unroll
        for (int n = 0; n < 2; ++n) {
            int feat = wid * 32 + n * 16 + l15;
            float bias = b[feat];
            #pragma unroll
            for (int j = 0; j < 4; ++j) {
                int node = nb + m * 16 + lhi * 4 + j;
                if (node < N) h[(size_t)node * 128 + feat] = acc[m][n][j] + bias;
            }
        }
    }
}

// ======== node GEMM (+fused BN), global B-frags, vector C-stores ========
__global__ __launch_bounds__(256, 4)
void node_gemm_f(float* __restrict__ h, float* __restrict__ agg,
                 const _Float16* __restrict__ WnL, const float* __restrict__ ABC,
                 float* __restrict__ Pd4, float* __restrict__ Ps4, int N, int doBN) {
    __shared__ __align__(16) _Float16 ht[32 * 128];
    const int tid = threadIdx.x;
    const int nb = blockIdx.x * 32;

    {
        int e = tid >> 3, t = tid & 7;
        int node = nb + e; bool ok = (node < N); if (!ok) node = N - 1;
        const int c0 = t * 16;
        float* hrow = h + (size_t)node * 128 + c0;
        __align__(16) _Float16 tmp[16];
        if (doBN && ok) {
            float* arow = agg + (size_t)node * 128 + c0;
            #pragma unroll
            for (int u = 0; u < 16; u += 4) {
                f32x4 av = *(const f32x4*)(arow + u);
                f32x4 hv = *(const f32x4*)(hrow + u);
                f32x4 Av = *(const f32x4*)(ABC + c0 + u);
                f32x4 Bv = *(const f32x4*)(ABC + 128 + c0 + u);
                f32x4 Cv = *(const f32x4*)(ABC + 256 + c0 + u);
                f32x4 xv;
                #pragma unroll
                for (int j = 0; j < 4; ++j)
                    xv[j] = fmaf(av[j], Av[j], fmaf(hv[j], Bv[j], Cv[j]));
                *(f32x4*)(hrow + u) = xv;
                *(f32x4*)(arow + u) = (f32x4){0.f, 0.f, 0.f, 0.f};
                #pragma unroll
                for (int j = 0; j < 4; ++j) tmp[u + j] = (_Float16)(xv[j] * HSCALE_INV);
            }
        } else {
            #pragma unroll
            for (int u = 0; u < 16; u += 4) {
                f32x4 hv = *(const f32x4*)(hrow + u);
                #pragma unroll
                for (int j = 0; j < 4; ++j) tmp[u + j] = (_Float16)(hv[j] * HSCALE_INV);
            }
        }
        int swz = (e & 7) << 4;
        *(u32x4*)((char*)ht + e * 256 + (((2 * t) * 16) ^ swz)) = *(u32x4*)tmp;
        *(u32x4*)((char*)ht + e * 256 + (((2 * t + 1) * 16) ^ swz)) = *(u32x4*)(tmp + 8);
    }
    __syncthreads();

    f32x4 acc[2][8];
    #pragma unroll
    for (int m = 0; m < 2; ++m)
        #pragma unroll
        for (int n = 0; n < 8; ++n) acc[m][n] = (f32x4){0.f, 0.f, 0.f, 0.f};

    const int wid = tid >> 6;
    const int lane = tid & 63;
    const int l15 = lane & 15;
    const int lhi = lane >> 4;
    const int swzA = (l15 & 7) << 4;

    #pragma unroll
    for (int c4 = 0; c4 < 4; ++c4) {
        half8 a[2];
        #pragma unroll
        for (int m = 0; m < 2; ++m) {
            int r = m * 16 + l15;
            a[m] = *(const half8*)((const char*)ht + r * 256 + ((c4 * 64 + lhi * 16) ^ swzA));
        }
        #pragma unroll
        for (int n = 0; n < 8; ++n) {
            int cb = wid * 8 + n;
            const half8 bf = *(const half8*)(WnL +
                             ((((size_t)c4 * 32 + cb) * 4 + lhi) * 16 + l15) * 8);
            #pragma unroll
            for (int m = 0; m < 2; ++m)
                acc[m][n] = __builtin_amdgcn_mfma_f32_16x16x32_f16(a[m], bf, acc[m][n], 0, 0, 0);
        }
    }

    float* base = (wid < 2) ? Pd4 : Ps4;
    const int gw = (wid & 1) * 2;
    #pragma unroll
    for (int m = 0; m < 2; ++m) {
        #pragma unroll
        for (int j = 0; j < 4; ++j) {
            int node = nb + m * 16 + lhi * 4 + j;
            if (node < N) {
                #pragma unroll
                for (int nn = 0; nn < 2; ++nn) {
                    f32x4 v = { acc[m][4 * nn + 0][j], acc[m][4 * nn + 1][j],
                                acc[m][4 * nn + 2][j], acc[m][4 * nn + 3][j] };
                    *(f32x4*)(base + (size_t)node * 256 + ((gw + nn) * 16 + l15) * 4) = v;
                }
            }
        }
    }
}

// ======== edge kernel v12: 64-edge block, 2x32-edge LDS time-slice (17KB) ======
__global__ __launch_bounds__(256, 6)
void edge_v12(const _Float16* __restrict__ eaH,
              const unsigned* __restrict__ sdS,
              const _Float16* __restrict__ WbL,
              const float* __restrict__ Pd4, const float* __restrict__ Ps4,
              const float* __restrict__ biasF, const float* __restrict__ biasS,
              float* __restrict__ agg) {
    __shared__ __align__(16) _Float16 eacc[32 * 256];   // 16 KB (half tile)
    __shared__ int srcl[64], dstl[64];

    const int tid = threadIdx.x;
    const int nblk = (int)gridDim.x;
    int lb = blockIdx.x;
    if ((nblk & 7) == 0) {
        int q = nblk >> 3;
        lb = (lb & 7) * q + (lb >> 3);
    }
    const int eb = lb * 64;

    if (tid < 64) {
        unsigned sd = sdS[eb + tid];
        srcl[tid] = (int)(sd & 0xFFFFu);
        dstl[tid] = (int)(sd >> 16);
    }

    const int wid = tid >> 6;
    const int lane = tid & 63;
    const int l15 = lane & 15;
    const int lhi = lane >> 4;

    f32x4 acc[4][4];
    #pragma unroll
    for (int m = 0; m < 4; ++m)
        #pragma unroll
        for (int n = 0; n < 4; ++n) acc[m][n] = (f32x4){0.f, 0.f, 0.f, 0.f};

    // MFMA for all 64 edges (K=64), A-frags from contiguous eaH
    #pragma unroll
    for (int c2 = 0; c2 < 2; ++c2) {
        half8 a[4];
        #pragma unroll
        for (int m = 0; m < 4; ++m) {
            int r = m * 16 + l15;
            a[m] = *(const half8*)(eaH + (size_t)(eb + r) * 64 + c2 * 32 + lhi * 8);
        }
        #pragma unroll
        for (int n = 0; n < 4; ++n) {
            int cb = wid * 4 + n;
            const half8 b = *(const half8*)(WbL +
                            ((((size_t)c2 * 16 + cb) * 4 + lhi) * 16 + l15) * 8);
            #pragma unroll
            for (int m = 0; m < 4; ++m)
                acc[m][n] = __builtin_amdgcn_mfma_f32_16x16x32_f16(a[m], b, acc[m][n], 0, 0, 0);
        }
    }

    const int g = (wid << 4) | l15;
    const int f0 = ((lane >> 4) << 5) | l15;
    f32x4 b4;
    b4[0] = biasF[f0] * LOG2E;
    b4[1] = biasS[f0] * LOG2E;
    b4[2] = biasF[f0 + 16] * LOG2E;
    b4[3] = biasS[f0 + 16] * LOG2E;

    int prevd = -1;
    f32x4 pdb;

    #pragma unroll
    for (int half = 0; half < 2; ++half) {
        // stage this half's acc to LDS (local rows 0..31)
        #pragma unroll
        for (int mm = 0; mm < 2; ++mm) {
            int m = half * 2 + mm;
            #pragma unroll
            for (int j = 0; j < 4; ++j) {
                int lr = mm * 16 + lhi * 4 + j;
                half4 hv;
                hv[0] = (_Float16)acc[m][0][j];
                hv[1] = (_Float16)acc[m][1][j];
                hv[2] = (_Float16)acc[m][2][j];
                hv[3] = (_Float16)acc[m][3][j];
                *(half4*)(eacc + lr * 256 + g * 4) = hv;
            }
        }
        __syncthreads();

        // gate: each wave walks 8 edges of this half
        const int rbase = half * 32 + wid * 8;
        float s0 = 0.f, s1 = 0.f;
        {
            int d0 = dstl[rbase];
            if (d0 != prevd) {
                pdb = *(const f32x4*)(Pd4 + (size_t)d0 * 256 + lane * 4);
                pdb += b4;
                prevd = d0;
            }
        }
        f32x4 psq[4];
        #pragma unroll
        for (int e = 0; e < 4; ++e)
            psq[e] = *(const f32x4*)(Ps4 + (size_t)srcl[rbase + e] * 256 + lane * 4);

        #pragma unroll
        for (int e = 0; e < 8; ++e) {
            int r = rbase + e;
            int d = dstl[r];
            if (d != prevd) {
                pdb = *(const f32x4*)(Pd4 + (size_t)d * 256 + lane * 4);
                pdb += b4;
                prevd = d;
            }
            f32x4 psv = psq[e & 3];
            if (e + 4 < 8)
                psq[e & 3] = *(const f32x4*)(Ps4 + (size_t)srcl[r + 4] * 256 + lane * 4);
            int lr = r - half * 32;
            half4 ev = *(const half4*)(eacc + lr * 256 + lane * 4);
            float fp0 = (float)ev[0] + pdb[0] + psv[0];
            float sp0 = (float)ev[1] + pdb[1] + psv[1];
            float fp1 = (float)ev[2] + pdb[2] + psv[2];
            float sp1 = (float)ev[3] + pdb[3] + psv[3];
            float sig0 = __builtin_amdgcn_rcpf(1.0f + exp2f(-fp0));
            float spl0 = fmaxf(sp0, 0.0f) + __log2f(1.0f + exp2f(-fabsf(sp0)));
            float sig1 = __builtin_amdgcn_rcpf(1.0f + exp2f(-fp1));
            float spl1 = fmaxf(sp1, 0.0f) + __log2f(1.0f + exp2f(-fabsf(sp1)));
            s0 += sig0 * spl0;
            s1 += sig1 * spl1;
            bool flush = (e == 7) || (dstl[r + 1] != d);
            if (flush) {
                atomicAdd(&agg[(size_t)d * 128 + f0], s0);
                atomicAdd(&agg[(size_t)d * 128 + f0 + 16], s1);
                s0 = 0.f; s1 = 0.f;
            }
        }
        if (half == 0) __syncthreads();   // protect eacc before next half's writes
    }
}

// ======== pool v3: fused final-BN + sorted-batch run aggregation ========
__global__ __launch_bounds__(256, 4)
void pool3_k(const float* __restrict__ agg, const float* __restrict__ h,
             const float* __restrict__ ABC5, const int* __restrict__ batch,
             float* __restrict__ sums, unsigned* __restrict__ maxs,
             float* __restrict__ counts, int N) {
    const int f = threadIdx.x & 127;
    const int half = threadIdx.x >> 7;
    const int nb = blockIdx.x * 64 + half * 32;
    if (nb >= N) return;

    const float A = ABC5[f], B = ABC5[128 + f], C = ABC5[256 + f];
    float s = 0.f;
    float mx = -3.4e38f;
    int prevg = -1;
    int runlen = 0;

    for (int e = 0; e < 32; ++e) {
        int n = nb + e;
        if (n >= N) break;
        int g = batch[n];
        if (g != prevg) {
            if (prevg >= 0) {
                atomicAdd(&sums[prevg * 128 + f], s);
                unsigned u = __float_as_uint(mx);
                unsigned key = (u & 0x80000000u) ? ~u : (u | 0x80000000u);
                atomicMax(&maxs[prevg * 128 + f], key);
                if (f == 0) atomicAdd(&counts[prevg], (float)runlen);
            }
            s = 0.f; mx = -3.4e38f; runlen = 0; prevg = g;
        }
        float v = fmaf(agg[(size_t)n * 128 + f], A, fmaf(h[(size_t)n * 128 + f], B, C));
        s += v;
        mx = fmaxf(mx, v);
        ++runlen;
    }
    if (prevg >= 0) {
        atomicAdd(&sums[prevg * 128 + f], s);
        unsigned u = __float_as_uint(mx);
        unsigned key = (u & 0x80000000u) ? ~u : (u | 0x80000000u);
        atomicMax(&maxs[prevg * 128 + f], key);
        if (f == 0) atomicAdd(&counts[prevg], (float)runlen);
    }
}

// ======== heads v2: transposed weights, f32x4 rows, 4-way ILP ========
__global__ __launch_bounds__(256)
void head_k2(const float* __restrict__ sums, const unsigned* __restrict__ maxs,
             const float* __restrict__ counts, const float* __restrict__ HT,
             const float* __restrict__ pb, const float* __restrict__ f1b,
             const float* __restrict__ f2b, const float* __restrict__ f3W,
             const float* __restrict__ f3b, const float* __restrict__ d1b,
             const float* __restrict__ d2b, float* __restrict__ out) {
    __shared__ float xp[256], emb[128], s1[256], s2[128], dd[256];
    int g = blockIdx.x, t = threadIdx.x;
    float cnt = counts[g];
    if (t < 128) {
        float mean = sums[g * 128 + t] / fmaxf(cnt, 1.0f);
        float mx = 0.0f;
        if (cnt > 0.0f) {
            unsigned key = maxs[g * 128 + t];
            unsigned u = (key & 0x80000000u) ? (key & 0x7fffffffu) : ~key;
            mx = __uint_as_float(u);
            if (!isfinite(mx)) mx = 0.0f;
        }
        xp[t] = mean;
        xp[128 + t] = mx;
    }
    __syncthreads();
    if (t < 128) {
        const float* w = HT + t * 256;
        float a0 = 0.f, a1 = 0.f, a2 = 0.f, a3 = 0.f;
        #pragma unroll
        for (int k = 0; k < 256; k += 4) {
            f32x4 wv = *(const f32x4*)(w + k);
            a0 = fmaf(xp[k + 0], wv[0], a0);
            a1 = fmaf(xp[k + 1], wv[1], a1);
            a2 = fmaf(xp[k + 2], wv[2], a2);
            a3 = fmaf(xp[k + 3], wv[3], a3);
        }
        emb[t] = fmaxf((a0 + a1) + (a2 + a3) + pb[t], 0.0f);
    }
    __syncthreads();
    {
        const float* w = HT + 32768 + t * 128;
        float a0 = 0.f, a1 = 0.f, a2 = 0.f, a3 = 0.f;
        #pragma unroll
        for (int k = 0; k < 128; k += 4) {
            f32x4 wv = *(const f32x4*)(w + k);
            a0 = fmaf(emb[k + 0], wv[0], a0);
            a1 = fmaf(emb[k + 1], wv[1], a1);
            a2 = fmaf(emb[k + 2], wv[2], a2);
            a3 = fmaf(emb[k + 3], wv[3], a3);
        }
        float a = (a0 + a1) + (a2 + a3) + f1b[t];
        s1[t] = a / (1.0f + __expf(-a));
    }
    __syncthreads();
    if (t < 128) {
        const float* w = HT + 65536 + t * 256;
        float a0 = 0.f, a1 = 0.f, a2 = 0.f, a3 = 0.f;
        #pragma unroll
        for (int k = 0; k < 256; k += 4) {
            f32x4 wv = *(const f32x4*)(w + k);
            a0 = fmaf(s1[k + 0], wv[0], a0);
            a1 = fmaf(s1[k + 1], wv[1], a1);
            a2 = fmaf(s1[k + 2], wv[2], a2);
            a3 = fmaf(s1[k + 3], wv[3], a3);
        }
        float a = (a0 + a1) + (a2 + a3) + f2b[t];
        s2[t] = a / (1.0f + __expf(-a));
    }
    {
        const float* w = HT + 98304 + t * 128;
        float a0 = 0.f, a1 = 0.f, a2 = 0.f, a3 = 0.f;
        #pragma unroll
        for (int k = 0; k < 128; k += 4) {
            f32x4 wv = *(const f32x4*)(w + k);
            a0 = fmaf(emb[k + 0], wv[0], a0);
            a1 = fmaf(emb[k + 1], wv[1], a1);
            a2 = fmaf(emb[k + 2], wv[2], a2);
            a3 = fmaf(emb[k + 3], wv[3], a3);
        }
        float a = (a0 + a1) + (a2 + a3) + d1b[t];
        dd[t] = a / (1.0f + __expf(-a));
    }
    __syncthreads();
    if (t == 0) {
        float a = f3b[0];
        for (int k = 0; k < 128; ++k) a = fmaf(s2[k], f3W[k], a);
        out[g] = a;
    }
    #pragma unroll
    for (int o = t; o < 384; o += 256) {
        const float* w = HT + 131072 + o * 256;
        float a0 = 0.f, a1 = 0.f, a2 = 0.f, a3 = 0.f;
        #pragma unroll
        for (int k = 0; k < 256; k += 4) {
            f32x4 wv = *(const f32x4*)(w + k);
            a0 = fmaf(dd[k + 0], wv[0], a0);
            a1 = fmaf(dd[k + 1], wv[1], a1);
            a2 = fmaf(dd[k + 2], wv[2], a2);
            a3 = fmaf(dd[k + 3], wv[3], a3);
        }
        out[128 + (size_t)g * 384 + o] = (a0 + a1) + (a2 + a3) + d2b[o];
    }
}

extern "C" void kernel_launch(void* const* d_in, const int* in_sizes, int n_in,
                              void* d_out, int out_size, void* d_ws, size_t ws_size,
                              hipStream_t stream) {
    const float* x       = (const float*)d_in[0];
    const int*   eidx    = (const int*)d_in[1];
    const float* ea      = (const float*)d_in[2];
    const int*   batch   = (const int*)d_in[3];
    const float* embW    = (const float*)d_in[4];
    const float* embB    = (const float*)d_in[5];
    const float* convWf  = (const float*)d_in[6];
    const float* convbf  = (const float*)d_in[7];
    const float* convWs  = (const float*)d_in[8];
    const float* convbs  = (const float*)d_in[9];
    const float* bing    = (const float*)d_in[10];
    const float* binb    = (const float*)d_in[11];
    const float* binm    = (const float*)d_in[12];
    const float* binv    = (const float*)d_in[13];
    const float* bog     = (const float*)d_in[14];
    const float* bob     = (const float*)d_in[15];
    const float* bom     = (const float*)d_in[16];
    const float* bov     = (const float*)d_in[17];
    const float* pW      = (const float*)d_in[18];
    const float* pb      = (const float*)d_in[19];
    const float* f1W     = (const float*)d_in[20];
    const float* f1b     = (const float*)d_in[21];
    const float* f2W     = (const float*)d_in[22];
    const float* f2b     = (const float*)d_in[23];
    const float* f3W     = (const float*)d_in[24];
    const float* f3b     = (const float*)d_in[25];
    const float* d1W     = (const float*)d_in[26];
    const float* d1b     = (const float*)d_in[27];
    const float* d2W     = (const float*)d_in[28];
    const float* d2b     = (const float*)d_in[29];

    const int N = in_sizes[0] / 98;
    const int E = in_sizes[1] / 2;
    const int* srcI = eidx;
    const int* dstI = eidx + E;

    // workspace layout
    char* ws = (char*)d_ws;
    float* h        = (float*)(ws);                     // 10,240,000
    float* agg      = (float*)(ws + 10240000);          // 10,240,000
    float* Pd4      = (float*)(ws + 20480000);          // 20,480,000
    float* Ps4      = (float*)(ws + 40960000);          // 20,480,000
    _Float16* Wn2   = (_Float16*)(ws + 61440000);       //    786,432
    _Float16* Wb2   = (_Float16*)(ws + 62226432);       //    196,608
    float* sums     = (float*)(ws + 62423040);          //     65,536
    unsigned* maxs  = (unsigned*)(ws + 62488576);       //     65,536
    float* gcnt     = (float*)(ws + 62554112);          //        512
    unsigned* sdS   = (unsigned*)(ws + 62554624);       //  1,280,000
    int* invE       = (int*)(ws + 63834624);            //  1,280,000
    _Float16* eaH   = (_Float16*)(ws + 65114624);       // 40,960,000
    float* ABC      = (float*)(ws + 106074624);         //      9,216
    _Float16* We    = (_Float16*)(ws + 106083840);      //     32,768
    float* HT       = (float*)(ws + 106116608);         //    917,504 -> 107,034,112
    // sort scratch aliased into Pd4 (dead before first node_gemm)
    int* nodeCnt    = (int*)(ws + 20480000);
    int* cursor     = nodeCnt + N;

    prep_wn2<<<(6 * 65536) / 256, 256, 0, stream>>>(convWf, convWs, Wn2);
    prep_wb2<<<(6 * 16384 + 255) / 256, 256, 0, stream>>>(convWf, convWs, Wb2);
    prep_we<<<64, 256, 0, stream>>>(embW, We);
    prep_ht<<<(229376 + 255) / 256, 256, 0, stream>>>(pW, f1W, f2W, d1W, d2W, HT);
    prep_bn<<<6, 128, 0, stream>>>(bing, binb, binm, binv, bog, bob, bom, bov, ABC);
    hipMemsetAsync(nodeCnt, 0, (size_t)N * 4, stream);
    hist_k<<<(E + 255) / 256, 256, 0, stream>>>(dstI, nodeCnt, E);
    scan_k<<<1, 256, 0, stream>>>(nodeCnt, cursor, N);
    scatter_k<<<(E + 255) / 256, 256, 0, stream>>>(srcI, dstI, cursor, sdS, invE, E);
    permute_ea2<<<(E + 3) / 4, 256, 0, stream>>>(ea, invE, eaH, E);

    const int n128 = N * 128;
    const int nblk = (N + 31) / 32;
    embed_mm<<<nblk, 256, 0, stream>>>(x, We, embB, h, N);

    hipMemsetAsync(agg, 0, (size_t)n128 * 4, stream);   // for layer 0's edge pass
    for (int i = 0; i < 6; ++i) {
        node_gemm_f<<<nblk, 256, 0, stream>>>(h, agg, Wn2 + (size_t)i * 65536,
                                              ABC + (size_t)(i - 1) * 384,
                                              Pd4, Ps4, N, (i > 0) ? 1 : 0);
        edge_v12<<<E / 64, 256, 0, stream>>>(eaH, sdS,
                                             Wb2 + (size_t)i * 16384,
                                             Pd4, Ps4, convbf + i * 128, convbs + i * 128, agg);
    }

    hipMemsetAsync(sums, 0, 65536 + 65536 + 512, stream);
    pool3_k<<<(N + 63) / 64, 256, 0, stream>>>(agg, h, ABC + 5 * 384, batch,
                                               sums, maxs, gcnt, N);
    head_k2<<<128, 256, 0, stream>>>(sums, maxs, gcnt, HT, pb, f1b, f2b, f3W, f3b,
                                     d1b, d2b, (float*)d_out);
}

// Round 22
// 638.265 us; speedup vs baseline: 1.4320x; 1.4320x over previous
//
#include <hip/hip_runtime.h>
#include <hip/hip_bf16.h>
#include <math.h>

typedef __attribute__((ext_vector_type(8))) _Float16 half8;
typedef __attribute__((ext_vector_type(4))) _Float16 half4;
typedef __attribute__((ext_vector_type(4))) float f32x4;
typedef __attribute__((ext_vector_type(4))) unsigned int u32x4;

#define FDIM 128
#define EPSBN 1e-5f
#define HSCALE_INV 0.015625f
#define WSCALE 64.0f
#define LOG2E 1.4426950408889634f
#define LN2   0.6931471805599453f

// ======== weight prep: node W in register-fragment layout, x64 x log2e ========
__global__ void prep_wn2(const float* __restrict__ Wf, const float* __restrict__ Ws,
                         _Float16* __restrict__ Wn2) {
    int idx = blockIdx.x * 256 + threadIdx.x;
    const int total = 6 * 65536;
    if (idx >= total) return;
    int j = idx & 7;
    int l15 = (idx >> 3) & 15;
    int lhi = (idx >> 7) & 3;
    int cb = (idx >> 9) & 31;
    int c4 = (idx >> 14) & 3;
    int i = idx >> 16;
    int col512 = cb * 16 + l15;
    int which = col512 >> 8;
    int colc = col512 & 255;
    int p = (colc >> 4) & 1;
    int f = ((colc >> 5) << 4) | (colc & 15);
    int k = c4 * 32 + lhi * 8 + j;
    int row = which * 128 + k;
    size_t o = ((size_t)i * 297 + row) * 128 + f;
    Wn2[idx] = (_Float16)((p ? Ws[o] : Wf[o]) * (WSCALE * LOG2E));
}

// ======== weight prep: ea part, register-fragment layout, x log2e ========
__global__ void prep_wb2(const float* __restrict__ Wf, const float* __restrict__ Ws,
                         _Float16* __restrict__ Wb2) {
    int idx = blockIdx.x * 256 + threadIdx.x;
    const int total = 6 * 16384;
    if (idx >= total) return;
    int j = idx & 7;
    int l15 = (idx >> 3) & 15;
    int lhi = (idx >> 7) & 3;
    int cb = (idx >> 9) & 15;
    int c2 = (idx >> 13) & 1;
    int i = idx >> 14;
    int k = c2 * 32 + lhi * 8 + j;
    int colc = cb * 16 + l15;
    int p = (colc >> 4) & 1;
    int f = ((colc >> 5) << 4) | (colc & 15);
    float v = 0.0f;
    if (k < 41) {
        size_t o = ((size_t)i * 297 + 256 + k) * 128 + f;
        v = (p ? Ws[o] : Wf[o]) * LOG2E;
    }
    Wb2[idx] = (_Float16)v;
}

// ======== weight prep: embed W fragments ========
__global__ void prep_we(const float* __restrict__ embW, _Float16* __restrict__ We) {
    int idx = blockIdx.x * 256 + threadIdx.x;
    if (idx >= 16384) return;
    int j = idx & 7;
    int l15 = (idx >> 3) & 15;
    int lhi = (idx >> 7) & 3;
    int cb = (idx >> 9) & 7;
    int c4 = (idx >> 12) & 3;
    int k = c4 * 32 + lhi * 8 + j;
    int f = cb * 16 + l15;
    We[idx] = (_Float16)((k < 98) ? embW[k * 128 + f] : 0.0f);
}

// ======== head weight transpose ========
__global__ void prep_ht(const float* __restrict__ pW, const float* __restrict__ f1W,
                        const float* __restrict__ f2W, const float* __restrict__ d1W,
                        const float* __restrict__ d2W, float* __restrict__ HT) {
    int idx = blockIdx.x * 256 + threadIdx.x;
    if (idx < 32768) {
        int o = idx >> 8, k = idx & 255;
        HT[o * 256 + k] = pW[k * 128 + o];
    } else if (idx < 65536) {
        int r = idx - 32768; int o = r >> 7, k = r & 127;
        HT[32768 + o * 128 + k] = f1W[k * 256 + o];
    } else if (idx < 98304) {
        int r = idx - 65536; int o = r >> 8, k = r & 255;
        HT[65536 + o * 256 + k] = f2W[k * 128 + o];
    } else if (idx < 131072) {
        int r = idx - 98304; int o = r >> 7, k = r & 127;
        HT[98304 + o * 128 + k] = d1W[k * 256 + o];
    } else if (idx < 229376) {
        int r = idx - 131072; int o = r >> 8, k = r & 255;
        HT[131072 + o * 256 + k] = d2W[k * 384 + o];
    }
}

// ======== BN affine composition ========
__global__ void prep_bn(const float* __restrict__ bing, const float* __restrict__ binb,
                        const float* __restrict__ binm, const float* __restrict__ binv,
                        const float* __restrict__ bog, const float* __restrict__ bob,
                        const float* __restrict__ bom, const float* __restrict__ bov,
                        float* __restrict__ ABC) {
    int idx = blockIdx.x * 128 + threadIdx.x;
    if (idx >= 6 * 128) return;
    int f = idx & 127;
    int i = idx >> 7;
    int o = i * 128 + f;
    float gin_ = bing[o] / sqrtf(binv[o] + EPSBN);
    float gout_ = bog[o] / sqrtf(bov[o] + EPSBN);
    ABC[i * 384 + f] = gin_ * gout_ * LN2;
    ABC[i * 384 + 128 + f] = gout_ + ((i > 0) ? 1.0f : 0.0f);
    ABC[i * 384 + 256 + f] = (binb[o] - binm[o] * gin_ - bom[o]) * gout_ + bob[o];
}

// ======== sorting ========
__global__ void hist_k(const int* __restrict__ dstI, int* __restrict__ cnt, int E) {
    int e = blockIdx.x * 256 + threadIdx.x;
    if (e < E) atomicAdd(&cnt[dstI[e]], 1);
}

__global__ void scan_k(const int* __restrict__ cnt, int* __restrict__ cursor, int N) {
    __shared__ int part[256];
    int t = threadIdx.x;
    int chunk = (N + 255) / 256;
    int lo = t * chunk, hi = lo + chunk; if (hi > N) hi = N;
    int s = 0;
    for (int i = lo; i < hi; ++i) s += cnt[i];
    part[t] = s;
    __syncthreads();
    for (int d = 1; d < 256; d <<= 1) {
        int v = (t >= d) ? part[t - d] : 0;
        __syncthreads();
        part[t] += v;
        __syncthreads();
    }
    int run = (t > 0) ? part[t - 1] : 0;
    for (int i = lo; i < hi; ++i) { cursor[i] = run; run += cnt[i]; }
}

__global__ void scatter_k(const int* __restrict__ srcI, const int* __restrict__ dstI,
                          int* __restrict__ cursor, unsigned* __restrict__ sdS,
                          int* __restrict__ invE, int E) {
    int e = blockIdx.x * 256 + threadIdx.x;
    if (e >= E) return;
    int d = dstI[e];
    int pos = atomicAdd(&cursor[d], 1);
    sdS[pos] = (unsigned)srcI[e] | ((unsigned)d << 16);
    invE[e] = pos;
}

__global__ void permute_ea2(const float* __restrict__ ea, const int* __restrict__ invE,
                            _Float16* __restrict__ eaH, int E) {
    int e = blockIdx.x * 4 + (threadIdx.x >> 6);
    int c = threadIdx.x & 63;
    if (e >= E) return;
    float v = (c < 41) ? ea[(size_t)e * 41 + c] : 0.0f;
    int pos = invE[e];
    eaH[(size_t)pos * 64 + c] = (_Float16)v;
}

// ======== embed via MFMA ========
__global__ __launch_bounds__(256, 4)
void embed_mm(const float* __restrict__ x, const _Float16* __restrict__ We,
              const float* __restrict__ b, float* __restrict__ h, int N) {
    __shared__ __align__(16) _Float16 xt[32 * 128];
    const int tid = threadIdx.x;
    const int nb = blockIdx.x * 32;

    {
        int e = tid >> 3, t = tid & 7;
        int node = nb + e; if (node >= N) node = N - 1;
        const float* row = x + (size_t)node * 98;
        __align__(16) _Float16 tmp[16];
        #pragma unroll
        for (int u = 0; u < 16; ++u) {
            int c = t * 16 + u;
            tmp[u] = (c < 98) ? (_Float16)row[c] : (_Float16)0.f;
        }
        int swz = (e & 7) << 4;
        *(u32x4*)((char*)xt + e * 256 + (((2 * t) * 16) ^ swz)) = *(u32x4*)tmp;
        *(u32x4*)((char*)xt + e * 256 + (((2 * t + 1) * 16) ^ swz)) = *(u32x4*)(tmp + 8);
    }
    __syncthreads();

    const int wid = tid >> 6;
    const int lane = tid & 63;
    const int l15 = lane & 15;
    const int lhi = lane >> 4;
    const int swzA = (l15 & 7) << 4;

    f32x4 acc[2][2];
    #pragma unroll
    for (int m = 0; m < 2; ++m)
        #pragma unroll
        for (int n = 0; n < 2; ++n) acc[m][n] = (f32x4){0.f, 0.f, 0.f, 0.f};

    #pragma unroll
    for (int c4 = 0; c4 < 4; ++c4) {
        half8 a[2];
        #pragma unroll
        for (int m = 0; m < 2; ++m) {
            int r = m * 16 + l15;
            a[m] = *(const half8*)((const char*)xt + r * 256 + ((c4 * 64 + lhi * 16) ^ swzA));
        }
        #pragma unroll
        for (int n = 0; n < 2; ++n) {
            int cb = wid * 2 + n;
            const half8 bf = *(const half8*)(We + ((((size_t)c4 * 8 + cb) * 4 + lhi) * 16 + l15) * 8);
            #pragma unroll
            for (int m = 0; m < 2; ++m)
                acc[m][n] = __builtin_amdgcn_mfma_f32_16x16x32_f16(a[m], bf, acc[m][n], 0, 0, 0);
        }
    }

    #pragma unroll
    for (int m = 0; m < 2; ++m) {
        #pragma unroll
        for (int n = 0; n < 2; ++n) {
            int feat = wid * 32 + n * 16 + l15;
            float bias = b[feat];
            #pragma unroll
            for (int j = 0; j < 4; ++j) {
                int node = nb + m * 16 + lhi * 4 + j;
                if (node < N) h[(size_t)node * 128 + feat] = acc[m][n][j] + bias;
            }
        }
    }
}

// ======== node GEMM (+fused BN), global B-frags, vector C-stores ========
__global__ __launch_bounds__(256, 4)
void node_gemm_f(float* __restrict__ h, float* __restrict__ agg,
                 const _Float16* __restrict__ WnL, const float* __restrict__ ABC,
                 float* __restrict__ Pd4, float* __restrict__ Ps4, int N, int doBN) {
    __shared__ __align__(16) _Float16 ht[32 * 128];
    const int tid = threadIdx.x;
    const int nb = blockIdx.x * 32;

    {
        int e = tid >> 3, t = tid & 7;
        int node = nb + e; bool ok = (node < N); if (!ok) node = N - 1;
        const int c0 = t * 16;
        float* hrow = h + (size_t)node * 128 + c0;
        __align__(16) _Float16 tmp[16];
        if (doBN && ok) {
            float* arow = agg + (size_t)node * 128 + c0;
            #pragma unroll
            for (int u = 0; u < 16; u += 4) {
                f32x4 av = *(const f32x4*)(arow + u);
                f32x4 hv = *(const f32x4*)(hrow + u);
                f32x4 Av = *(const f32x4*)(ABC + c0 + u);
                f32x4 Bv = *(const f32x4*)(ABC + 128 + c0 + u);
                f32x4 Cv = *(const f32x4*)(ABC + 256 + c0 + u);
                f32x4 xv;
                #pragma unroll
                for (int j = 0; j < 4; ++j)
                    xv[j] = fmaf(av[j], Av[j], fmaf(hv[j], Bv[j], Cv[j]));
                *(f32x4*)(hrow + u) = xv;
                *(f32x4*)(arow + u) = (f32x4){0.f, 0.f, 0.f, 0.f};
                #pragma unroll
                for (int j = 0; j < 4; ++j) tmp[u + j] = (_Float16)(xv[j] * HSCALE_INV);
            }
        } else {
            #pragma unroll
            for (int u = 0; u < 16; u += 4) {
                f32x4 hv = *(const f32x4*)(hrow + u);
                #pragma unroll
                for (int j = 0; j < 4; ++j) tmp[u + j] = (_Float16)(hv[j] * HSCALE_INV);
            }
        }
        int swz = (e & 7) << 4;
        *(u32x4*)((char*)ht + e * 256 + (((2 * t) * 16) ^ swz)) = *(u32x4*)tmp;
        *(u32x4*)((char*)ht + e * 256 + (((2 * t + 1) * 16) ^ swz)) = *(u32x4*)(tmp + 8);
    }
    __syncthreads();

    f32x4 acc[2][8];
    #pragma unroll
    for (int m = 0; m < 2; ++m)
        #pragma unroll
        for (int n = 0; n < 8; ++n) acc[m][n] = (f32x4){0.f, 0.f, 0.f, 0.f};

    const int wid = tid >> 6;
    const int lane = tid & 63;
    const int l15 = lane & 15;
    const int lhi = lane >> 4;
    const int swzA = (l15 & 7) << 4;

    #pragma unroll
    for (int c4 = 0; c4 < 4; ++c4) {
        half8 a[2];
        #pragma unroll
        for (int m = 0; m < 2; ++m) {
            int r = m * 16 + l15;
            a[m] = *(const half8*)((const char*)ht + r * 256 + ((c4 * 64 + lhi * 16) ^ swzA));
        }
        #pragma unroll
        for (int n = 0; n < 8; ++n) {
            int cb = wid * 8 + n;
            const half8 bf = *(const half8*)(WnL +
                             ((((size_t)c4 * 32 + cb) * 4 + lhi) * 16 + l15) * 8);
            #pragma unroll
            for (int m = 0; m < 2; ++m)
                acc[m][n] = __builtin_amdgcn_mfma_f32_16x16x32_f16(a[m], bf, acc[m][n], 0, 0, 0);
        }
    }

    float* base = (wid < 2) ? Pd4 : Ps4;
    const int gw = (wid & 1) * 2;
    #pragma unroll
    for (int m = 0; m < 2; ++m) {
        #pragma unroll
        for (int j = 0; j < 4; ++j) {
            int node = nb + m * 16 + lhi * 4 + j;
            if (node < N) {
                #pragma unroll
                for (int nn = 0; nn < 2; ++nn) {
                    f32x4 v = { acc[m][4 * nn + 0][j], acc[m][4 * nn + 1][j],
                                acc[m][4 * nn + 2][j], acc[m][4 * nn + 3][j] };
                    *(f32x4*)(base + (size_t)node * 256 + ((gw + nn) * 16 + l15) * 4) = v;
                }
            }
        }
    }
}

// ======== edge kernel v11 (proven 63us): 4-deep psv pipeline + XCD swizzle =====
__global__ __launch_bounds__(256, 4)
void edge_v11(const _Float16* __restrict__ eaH,
              const unsigned* __restrict__ sdS,
              const _Float16* __restrict__ WbL,
              const float* __restrict__ Pd4, const float* __restrict__ Ps4,
              const float* __restrict__ biasF, const float* __restrict__ biasS,
              float* __restrict__ agg) {
    __shared__ __align__(16) _Float16 eacc[64 * 256];   // 32 KB
    __shared__ int srcl[64], dstl[64];

    const int tid = threadIdx.x;
    const int nblk = (int)gridDim.x;
    int lb = blockIdx.x;
    if ((nblk & 7) == 0) {
        int q = nblk >> 3;
        lb = (lb & 7) * q + (lb >> 3);
    }
    const int eb = lb * 64;

    if (tid < 64) {
        unsigned sd = sdS[eb + tid];
        srcl[tid] = (int)(sd & 0xFFFFu);
        dstl[tid] = (int)(sd >> 16);
    }

    const int wid = tid >> 6;
    const int lane = tid & 63;
    const int l15 = lane & 15;
    const int lhi = lane >> 4;

    f32x4 acc[4][4];
    #pragma unroll
    for (int m = 0; m < 4; ++m)
        #pragma unroll
        for (int n = 0; n < 4; ++n) acc[m][n] = (f32x4){0.f, 0.f, 0.f, 0.f};

    #pragma unroll
    for (int c2 = 0; c2 < 2; ++c2) {
        half8 a[4];
        #pragma unroll
        for (int m = 0; m < 4; ++m) {
            int r = m * 16 + l15;
            a[m] = *(const half8*)(eaH + (size_t)(eb + r) * 64 + c2 * 32 + lhi * 8);
        }
        #pragma unroll
        for (int n = 0; n < 4; ++n) {
            int cb = wid * 4 + n;
            const half8 b = *(const half8*)(WbL +
                            ((((size_t)c2 * 16 + cb) * 4 + lhi) * 16 + l15) * 8);
            #pragma unroll
            for (int m = 0; m < 4; ++m)
                acc[m][n] = __builtin_amdgcn_mfma_f32_16x16x32_f16(a[m], b, acc[m][n], 0, 0, 0);
        }
    }

    {
        const int g = (wid << 4) | l15;
        #pragma unroll
        for (int m = 0; m < 4; ++m) {
            #pragma unroll
            for (int j = 0; j < 4; ++j) {
                int r = m * 16 + lhi * 4 + j;
                half4 hv;
                hv[0] = (_Float16)acc[m][0][j];
                hv[1] = (_Float16)acc[m][1][j];
                hv[2] = (_Float16)acc[m][2][j];
                hv[3] = (_Float16)acc[m][3][j];
                *(half4*)(eacc + r * 256 + g * 4) = hv;
            }
        }
    }
    __syncthreads();

    const int f0 = ((lane >> 4) << 5) | l15;
    f32x4 b4;
    b4[0] = biasF[f0] * LOG2E;
    b4[1] = biasS[f0] * LOG2E;
    b4[2] = biasF[f0 + 16] * LOG2E;
    b4[3] = biasS[f0 + 16] * LOG2E;
    const int rbase = wid * 16;

    float s0 = 0.f, s1 = 0.f;
    int prevd = dstl[rbase];
    f32x4 pdb = *(const f32x4*)(Pd4 + (size_t)prevd * 256 + lane * 4);
    pdb += b4;

    f32x4 psq[4];
    #pragma unroll
    for (int e = 0; e < 4; ++e)
        psq[e] = *(const f32x4*)(Ps4 + (size_t)srcl[rbase + e] * 256 + lane * 4);

    #pragma unroll
    for (int e = 0; e < 16; ++e) {
        int r = rbase + e;
        int d = dstl[r];
        if (d != prevd) {
            pdb = *(const f32x4*)(Pd4 + (size_t)d * 256 + lane * 4);
            pdb += b4;
            prevd = d;
        }
        f32x4 psv = psq[e & 3];
        if (e + 4 < 16)
            psq[e & 3] = *(const f32x4*)(Ps4 + (size_t)srcl[r + 4] * 256 + lane * 4);
        half4 ev = *(const half4*)(eacc + r * 256 + lane * 4);
        float fp0 = (float)ev[0] + pdb[0] + psv[0];
        float sp0 = (float)ev[1] + pdb[1] + psv[1];
        float fp1 = (float)ev[2] + pdb[2] + psv[2];
        float sp1 = (float)ev[3] + pdb[3] + psv[3];
        float sig0 = __builtin_amdgcn_rcpf(1.0f + exp2f(-fp0));
        float spl0 = fmaxf(sp0, 0.0f) + __log2f(1.0f + exp2f(-fabsf(sp0)));
        float sig1 = __builtin_amdgcn_rcpf(1.0f + exp2f(-fp1));
        float spl1 = fmaxf(sp1, 0.0f) + __log2f(1.0f + exp2f(-fabsf(sp1)));
        s0 += sig0 * spl0;
        s1 += sig1 * spl1;
        bool flush = (e == 15) || (dstl[r + 1] != d);
        if (flush) {
            atomicAdd(&agg[(size_t)d * 128 + f0], s0);
            atomicAdd(&agg[(size_t)d * 128 + f0 + 16], s1);
            s0 = 0.f; s1 = 0.f;
        }
    }
}

// ======== pool v3: fused final-BN + sorted-batch run aggregation ========
__global__ __launch_bounds__(256, 4)
void pool3_k(const float* __restrict__ agg, const float* __restrict__ h,
             const float* __restrict__ ABC5, const int* __restrict__ batch,
             float* __restrict__ sums, unsigned* __restrict__ maxs,
             float* __restrict__ counts, int N) {
    const int f = threadIdx.x & 127;
    const int half = threadIdx.x >> 7;
    const int nb = blockIdx.x * 64 + half * 32;
    if (nb >= N) return;

    const float A = ABC5[f], B = ABC5[128 + f], C = ABC5[256 + f];
    float s = 0.f;
    float mx = -3.4e38f;
    int prevg = -1;
    int runlen = 0;

    for (int e = 0; e < 32; ++e) {
        int n = nb + e;
        if (n >= N) break;
        int g = batch[n];
        if (g != prevg) {
            if (prevg >= 0) {
                atomicAdd(&sums[prevg * 128 + f], s);
                unsigned u = __float_as_uint(mx);
                unsigned key = (u & 0x80000000u) ? ~u : (u | 0x80000000u);
                atomicMax(&maxs[prevg * 128 + f], key);
                if (f == 0) atomicAdd(&counts[prevg], (float)runlen);
            }
            s = 0.f; mx = -3.4e38f; runlen = 0; prevg = g;
        }
        float v = fmaf(agg[(size_t)n * 128 + f], A, fmaf(h[(size_t)n * 128 + f], B, C));
        s += v;
        mx = fmaxf(mx, v);
        ++runlen;
    }
    if (prevg >= 0) {
        atomicAdd(&sums[prevg * 128 + f], s);
        unsigned u = __float_as_uint(mx);
        unsigned key = (u & 0x80000000u) ? ~u : (u | 0x80000000u);
        atomicMax(&maxs[prevg * 128 + f], key);
        if (f == 0) atomicAdd(&counts[prevg], (float)runlen);
    }
}

// ======== heads v2 ========
__global__ __launch_bounds__(256)
void head_k2(const float* __restrict__ sums, const unsigned* __restrict__ maxs,
             const float* __restrict__ counts, const float* __restrict__ HT,
             const float* __restrict__ pb, const float* __restrict__ f1b,
             const float* __restrict__ f2b, const float* __restrict__ f3W,
             const float* __restrict__ f3b, const float* __restrict__ d1b,
             const float* __restrict__ d2b, float* __restrict__ out) {
    __shared__ float xp[256], emb[128], s1[256], s2[128], dd[256];
    int g = blockIdx.x, t = threadIdx.x;
    float cnt = counts[g];
    if (t < 128) {
        float mean = sums[g * 128 + t] / fmaxf(cnt, 1.0f);
        float mx = 0.0f;
        if (cnt > 0.0f) {
            unsigned key = maxs[g * 128 + t];
            unsigned u = (key & 0x80000000u) ? (key & 0x7fffffffu) : ~key;
            mx = __uint_as_float(u);
            if (!isfinite(mx)) mx = 0.0f;
        }
        xp[t] = mean;
        xp[128 + t] = mx;
    }
    __syncthreads();
    if (t < 128) {
        const float* w = HT + t * 256;
        float a0 = 0.f, a1 = 0.f, a2 = 0.f, a3 = 0.f;
        #pragma unroll
        for (int k = 0; k < 256; k += 4) {
            f32x4 wv = *(const f32x4*)(w + k);
            a0 = fmaf(xp[k + 0], wv[0], a0);
            a1 = fmaf(xp[k + 1], wv[1], a1);
            a2 = fmaf(xp[k + 2], wv[2], a2);
            a3 = fmaf(xp[k + 3], wv[3], a3);
        }
        emb[t] = fmaxf((a0 + a1) + (a2 + a3) + pb[t], 0.0f);
    }
    __syncthreads();
    {
        const float* w = HT + 32768 + t * 128;
        float a0 = 0.f, a1 = 0.f, a2 = 0.f, a3 = 0.f;
        #pragma unroll
        for (int k = 0; k < 128; k += 4) {
            f32x4 wv = *(const f32x4*)(w + k);
            a0 = fmaf(emb[k + 0], wv[0], a0);
            a1 = fmaf(emb[k + 1], wv[1], a1);
            a2 = fmaf(emb[k + 2], wv[2], a2);
            a3 = fmaf(emb[k + 3], wv[3], a3);
        }
        float a = (a0 + a1) + (a2 + a3) + f1b[t];
        s1[t] = a / (1.0f + __expf(-a));
    }
    __syncthreads();
    if (t < 128) {
        const float* w = HT + 65536 + t * 256;
        float a0 = 0.f, a1 = 0.f, a2 = 0.f, a3 = 0.f;
        #pragma unroll
        for (int k = 0; k < 256; k += 4) {
            f32x4 wv = *(const f32x4*)(w + k);
            a0 = fmaf(s1[k + 0], wv[0], a0);
            a1 = fmaf(s1[k + 1], wv[1], a1);
            a2 = fmaf(s1[k + 2], wv[2], a2);
            a3 = fmaf(s1[k + 3], wv[3], a3);
        }
        float a = (a0 + a1) + (a2 + a3) + f2b[t];
        s2[t] = a / (1.0f + __expf(-a));
    }
    {
        const float* w = HT + 98304 + t * 128;
        float a0 = 0.f, a1 = 0.f, a2 = 0.f, a3 = 0.f;
        #pragma unroll
        for (int k = 0; k < 128; k += 4) {
            f32x4 wv = *(const f32x4*)(w + k);
            a0 = fmaf(emb[k + 0], wv[0], a0);
            a1 = fmaf(emb[k + 1], wv[1], a1);
            a2 = fmaf(emb[k + 2], wv[2], a2);
            a3 = fmaf(emb[k + 3], wv[3], a3);
        }
        float a = (a0 + a1) + (a2 + a3) + d1b[t];
        dd[t] = a / (1.0f + __expf(-a));
    }
    __syncthreads();
    if (t == 0) {
        float a = f3b[0];
        for (int k = 0; k < 128; ++k) a = fmaf(s2[k], f3W[k], a);
        out[g] = a;
    }
    #pragma unroll
    for (int o = t; o < 384; o += 256) {
        const float* w = HT + 131072 + o * 256;
        float a0 = 0.f, a1 = 0.f, a2 = 0.f, a3 = 0.f;
        #pragma unroll
        for (int k = 0; k < 256; k += 4) {
            f32x4 wv = *(const f32x4*)(w + k);
            a0 = fmaf(dd[k + 0], wv[0], a0);
            a1 = fmaf(dd[k + 1], wv[1], a1);
            a2 = fmaf(dd[k + 2], wv[2], a2);
            a3 = fmaf(dd[k + 3], wv[3], a3);
        }
        out[128 + (size_t)g * 384 + o] = (a0 + a1) + (a2 + a3) + d2b[o];
    }
}

extern "C" void kernel_launch(void* const* d_in, const int* in_sizes, int n_in,
                              void* d_out, int out_size, void* d_ws, size_t ws_size,
                              hipStream_t stream) {
    const float* x       = (const float*)d_in[0];
    const int*   eidx    = (const int*)d_in[1];
    const float* ea      = (const float*)d_in[2];
    const int*   batch   = (const int*)d_in[3];
    const float* embW    = (const float*)d_in[4];
    const float* embB    = (const float*)d_in[5];
    const float* convWf  = (const float*)d_in[6];
    const float* convbf  = (const float*)d_in[7];
    const float* convWs  = (const float*)d_in[8];
    const float* convbs  = (const float*)d_in[9];
    const float* bing    = (const float*)d_in[10];
    const float* binb    = (const float*)d_in[11];
    const float* binm    = (const float*)d_in[12];
    const float* binv    = (const float*)d_in[13];
    const float* bog     = (const float*)d_in[14];
    const float* bob     = (const float*)d_in[15];
    const float* bom     = (const float*)d_in[16];
    const float* bov     = (const float*)d_in[17];
    const float* pW      = (const float*)d_in[18];
    const float* pb      = (const float*)d_in[19];
    const float* f1W     = (const float*)d_in[20];
    const float* f1b     = (const float*)d_in[21];
    const float* f2W     = (const float*)d_in[22];
    const float* f2b     = (const float*)d_in[23];
    const float* f3W     = (const float*)d_in[24];
    const float* f3b     = (const float*)d_in[25];
    const float* d1W     = (const float*)d_in[26];
    const float* d1b     = (const float*)d_in[27];
    const float* d2W     = (const float*)d_in[28];
    const float* d2b     = (const float*)d_in[29];

    const int N = in_sizes[0] / 98;
    const int E = in_sizes[1] / 2;
    const int* srcI = eidx;
    const int* dstI = eidx + E;

    // workspace layout
    char* ws = (char*)d_ws;
    float* h        = (float*)(ws);                     // 10,240,000
    float* agg      = (float*)(ws + 10240000);          // 10,240,000
    float* Pd4      = (float*)(ws + 20480000);          // 20,480,000
    float* Ps4      = (float*)(ws + 40960000);          // 20,480,000
    _Float16* Wn2   = (_Float16*)(ws + 61440000);       //    786,432
    _Float16* Wb2   = (_Float16*)(ws + 62226432);       //    196,608
    float* sums     = (float*)(ws + 62423040);          //     65,536
    unsigned* maxs  = (unsigned*)(ws + 62488576);       //     65,536
    float* gcnt     = (float*)(ws + 62554112);          //        512
    unsigned* sdS   = (unsigned*)(ws + 62554624);       //  1,280,000
    int* invE       = (int*)(ws + 63834624);            //  1,280,000
    _Float16* eaH   = (_Float16*)(ws + 65114624);       // 40,960,000
    float* ABC      = (float*)(ws + 106074624);         //      9,216
    _Float16* We    = (_Float16*)(ws + 106083840);      //     32,768
    float* HT       = (float*)(ws + 106116608);         //    917,504 -> 107,034,112
    // sort scratch aliased into Pd4 (dead before first node_gemm)
    int* nodeCnt    = (int*)(ws + 20480000);
    int* cursor     = nodeCnt + N;

    prep_wn2<<<(6 * 65536) / 256, 256, 0, stream>>>(convWf, convWs, Wn2);
    prep_wb2<<<(6 * 16384 + 255) / 256, 256, 0, stream>>>(convWf, convWs, Wb2);
    prep_we<<<64, 256, 0, stream>>>(embW, We);
    prep_ht<<<(229376 + 255) / 256, 256, 0, stream>>>(pW, f1W, f2W, d1W, d2W, HT);
    prep_bn<<<6, 128, 0, stream>>>(bing, binb, binm, binv, bog, bob, bom, bov, ABC);
    hipMemsetAsync(nodeCnt, 0, (size_t)N * 4, stream);
    hist_k<<<(E + 255) / 256, 256, 0, stream>>>(dstI, nodeCnt, E);
    scan_k<<<1, 256, 0, stream>>>(nodeCnt, cursor, N);
    scatter_k<<<(E + 255) / 256, 256, 0, stream>>>(srcI, dstI, cursor, sdS, invE, E);
    permute_ea2<<<(E + 3) / 4, 256, 0, stream>>>(ea, invE, eaH, E);

    const int n128 = N * 128;
    const int nblk = (N + 31) / 32;
    embed_mm<<<nblk, 256, 0, stream>>>(x, We, embB, h, N);

    hipMemsetAsync(agg, 0, (size_t)n128 * 4, stream);
    for (int i = 0; i < 6; ++i) {
        node_gemm_f<<<nblk, 256, 0, stream>>>(h, agg, Wn2 + (size_t)i * 65536,
                                              ABC + (size_t)(i - 1) * 384,
                                              Pd4, Ps4, N, (i > 0) ? 1 : 0);
        edge_v11<<<E / 64, 256, 0, stream>>>(eaH, sdS,
                                             Wb2 + (size_t)i * 16384,
                                             Pd4, Ps4, convbf + i * 128, convbs + i * 128, agg);
    }

    hipMemsetAsync(sums, 0, 65536 + 65536 + 512, stream);
    pool3_k<<<(N + 63) / 64, 256, 0, stream>>>(agg, h, ABC + 5 * 384, batch,
                                               sums, maxs, gcnt, N);
    head_k2<<<128, 256, 0, stream>>>(sums, maxs, gcnt, HT, pb, f1b, f2b, f3W, f3b,
                                     d1b, d2b, (float*)d_out);
}